// Round 2
// baseline (3583.686 us; speedup 1.0000x reference)
//
#include <hip/hip_runtime.h>

#ifndef __has_builtin
#define __has_builtin(x) 0
#endif

__device__ __forceinline__ float fexp2(float x) {
#if __has_builtin(__builtin_amdgcn_exp2f)
    return __builtin_amdgcn_exp2f(x);   // v_exp_f32 (2^x)
#else
    return exp2f(x);
#endif
}
__device__ __forceinline__ float flog2(float x) {
#if __has_builtin(__builtin_amdgcn_logf)
    return __builtin_amdgcn_logf(x);    // v_log_f32 (log2 x)
#else
    return log2f(x);
#endif
}

#define NMAXN 128
#define DD    64
#define MAX_ITERS 500

// -1e5 * log2(e)  (NEG surrogate in log2 domain)
#define NEG2  (-144269.50408889634f)
// -(log2(e) / eps), eps = 1e-3 : logK2 = M * LKSC
#define LKSC  (-1442.6950408889634f)
// -(eps * ln2) : out = acc * OUTSC
#define OUTSC (-6.931471805599453e-4f)

struct SmemStage {
    float A[NMAXN * 33];   // set1 chunk [128][32] padded
    float B[NMAXN * 33];   // set2 chunk
    float nA[NMAXN];       // row norms set1
    float nB[NMAXN];       // row norms set2
};
struct SmemSink {
    float mVm[2 * NMAXN];  // v-phase: per-half column max
    float mVs[2 * NMAXN];  // v-phase: per-half column sum
    float mUm[2 * NMAXN];  // u-phase: per-half row max
    float mUs[2 * NMAXN];  // u-phase: per-half row sum
};
union SmemU {
    SmemStage st;
    SmemSink  sk;
};

__global__ __launch_bounds__(256, 2)
void wasserstein_kernel(const float* __restrict__ x1, const float* __restrict__ x2,
                        const int* __restrict__ sz1, const int* __restrict__ sz2,
                        float* __restrict__ out)
{
    __shared__ SmemU sm;
    __shared__ int   soff[8];
    __shared__ float swred[4];
    __shared__ int   flagsA[2];   // state(k) != state(k-1)  (parity-indexed)
    __shared__ int   flagsB[2];   // state(k) != state(k-2)

    const int b    = blockIdx.x;
    const int tid  = threadIdx.x;
    const int w    = tid >> 6;        // wave 0..3
    const int lane = tid & 63;
    const int tx8  = lane & 7;        // col-within-wave
    const int ty8  = lane >> 3;       // row-within-wave (0..7)
    const int ty   = ((w >> 1) << 3) | ty8;  // 0..15
    const int tx   = ((w & 1) << 3) | tx8;   // 0..15
    const int R0   = ty << 3;         // first owned row
    const int C0   = tx << 3;         // first owned col
    const int halfR = (w >> 1) & 1;   // row-half (for reduce over rows)
    const int halfC = w & 1;          // col-half (for reduce over cols)

    // ---- exclusive prefix sums of sizes (ragged offsets) ----
    int a1 = 0, a2 = 0;
    for (int kk = tid; kk < b; kk += 256) { a1 += sz1[kk]; a2 += sz2[kk]; }
#pragma unroll
    for (int d = 1; d < 64; d <<= 1) {
        a1 += __shfl_xor(a1, d);
        a2 += __shfl_xor(a2, d);
    }
    if (lane == 0) { soff[w] = a1; soff[4 + w] = a2; }
    if (tid < NMAXN) { sm.st.nA[tid] = 0.f; sm.st.nB[tid] = 0.f; }
    __syncthreads();
    const int off1 = soff[0] + soff[1] + soff[2] + soff[3];
    const int off2 = soff[4] + soff[5] + soff[6] + soff[7];
    const int n1 = sz1[b];
    const int n2 = sz2[b];

    // ---- stage sets in D-chunks of 32, accumulate dots + norms ----
    float dot[8][8];
#pragma unroll
    for (int r = 0; r < 8; ++r)
#pragma unroll
        for (int c = 0; c < 8; ++c) dot[r][c] = 0.f;

    const int srow  = tid >> 1;  // 0..127
    const int shalf = tid & 1;   // 16-float half of chunk

    for (int ch = 0; ch < 2; ++ch) {
        const float* p1 = x1 + (size_t)(off1 + srow) * DD + ch * 32 + shalf * 16;
        const float* p2 = x2 + (size_t)(off2 + srow) * DD + ch * 32 + shalf * 16;
        const bool ok1 = srow < n1;
        const bool ok2 = srow < n2;
        float va[16], vb[16];
#pragma unroll
        for (int q = 0; q < 4; ++q) {
            float4 t1 = ok1 ? ((const float4*)p1)[q] : make_float4(0.f, 0.f, 0.f, 0.f);
            float4 t2 = ok2 ? ((const float4*)p2)[q] : make_float4(0.f, 0.f, 0.f, 0.f);
            va[4*q+0] = t1.x; va[4*q+1] = t1.y; va[4*q+2] = t1.z; va[4*q+3] = t1.w;
            vb[4*q+0] = t2.x; vb[4*q+1] = t2.y; vb[4*q+2] = t2.z; vb[4*q+3] = t2.w;
        }
        float s1 = 0.f, s2 = 0.f;
        const int cb = shalf * 16;
#pragma unroll
        for (int q = 0; q < 16; ++q) {
            sm.st.A[srow * 33 + cb + q] = va[q];
            sm.st.B[srow * 33 + cb + q] = vb[q];
            s1 += va[q] * va[q];
            s2 += vb[q] * vb[q];
        }
        s1 += __shfl_xor(s1, 1);
        s2 += __shfl_xor(s2, 1);
        if (shalf == 0) { sm.st.nA[srow] += s1; sm.st.nB[srow] += s2; }
        __syncthreads();
#pragma unroll 2
        for (int d = 0; d < 32; ++d) {
            float av[8], bv[8];
#pragma unroll
            for (int r = 0; r < 8; ++r) av[r] = sm.st.A[(R0 + r) * 33 + d];
#pragma unroll
            for (int c = 0; c < 8; ++c) bv[c] = sm.st.B[(C0 + c) * 33 + d];
#pragma unroll
            for (int r = 0; r < 8; ++r)
#pragma unroll
                for (int c = 0; c < 8; ++c)
                    dot[r][c] = fmaf(av[r], bv[c], dot[r][c]);
        }
        __syncthreads();
    }

    float rn1[8], rn2[8];
#pragma unroll
    for (int r = 0; r < 8; ++r) rn1[r] = sm.st.nA[R0 + r];
#pragma unroll
    for (int c = 0; c < 8; ++c) rn2[c] = sm.st.nB[C0 + c];

    // logK2 = -M * log2e/eps, M = ||a||^2 + ||b||^2 - 2ab (clamped >= 0)
    float lk[8][8];
#pragma unroll
    for (int r = 0; r < 8; ++r)
#pragma unroll
        for (int c = 0; c < 8; ++c) {
            float M = rn1[r] + rn2[c] - 2.f * dot[r][c];
            M = fmaxf(M, 0.f);
            lk[r][c] = M * LKSC;
        }

    // ---- Sinkhorn init (log2 domain); u,v live in registers ----
    float u_old[8], v_old[8], u_p2[8], v_p2[8], la[8], lb[8];
    const float lbv = flog2((float)n1) - flog2((float)n2);
#pragma unroll
    for (int r = 0; r < 8; ++r) {
        u_old[r] = 0.f;
        u_p2[r]  = __uint_as_float(0xFFFFFFFFu);  // never-equal sentinel
        la[r]    = (R0 + r < n1) ? 0.f : NEG2;
    }
#pragma unroll
    for (int c = 0; c < 8; ++c) {
        v_old[c] = 0.f;
        v_p2[c]  = __uint_as_float(0xFFFFFFFFu);
        lb[c]    = (C0 + c < n2) ? lbv : NEG2;
    }
    if (tid == 0) { flagsA[0] = flagsA[1] = 1; flagsB[0] = flagsB[1] = 1; }
    __syncthreads();   // retire staging view; flags visible

    float tt[8][8];
    for (int k = 0; k < MAX_ITERS; ++k) {
        // ========== phase V: v_j = lb_j - lse_i(lk_ij + u_i) ==========
        float mx[8], sc[8];
#pragma unroll
        for (int c = 0; c < 8; ++c) { tt[0][c] = lk[0][c] + u_old[0]; mx[c] = tt[0][c]; }
#pragma unroll
        for (int r = 1; r < 8; ++r)
#pragma unroll
            for (int c = 0; c < 8; ++c) {
                tt[r][c] = lk[r][c] + u_old[r];
                mx[c] = fmaxf(mx[c], tt[r][c]);
            }
#pragma unroll
        for (int c = 0; c < 8; ++c) {   // in-wave reduce over ty8 (rows)
            mx[c] = fmaxf(mx[c], __shfl_xor(mx[c], 8));
            mx[c] = fmaxf(mx[c], __shfl_xor(mx[c], 16));
            mx[c] = fmaxf(mx[c], __shfl_xor(mx[c], 32));
        }
#pragma unroll
        for (int c = 0; c < 8; ++c) sc[c] = fexp2(tt[0][c] - mx[c]);
#pragma unroll
        for (int r = 1; r < 8; ++r)
#pragma unroll
            for (int c = 0; c < 8; ++c) sc[c] += fexp2(tt[r][c] - mx[c]);
#pragma unroll
        for (int c = 0; c < 8; ++c) {
            sc[c] += __shfl_xor(sc[c], 8);
            sc[c] += __shfl_xor(sc[c], 16);
            sc[c] += __shfl_xor(sc[c], 32);
        }
        if (ty8 == 0) {
#pragma unroll
            for (int c = 0; c < 8; ++c) {
                sm.sk.mVm[halfR * NMAXN + C0 + c] = mx[c];
                sm.sk.mVs[halfR * NMAXN + C0 + c] = sc[c];
            }
        }
        __syncthreads();                               // B1

        // delayed convergence check (flags written by iter k-1)
        const int fprev  = flagsA[(k - 1) & 1];
        const int f2prev = flagsB[(k - 1) & 1];
        if (fprev == 0) break;          // fixed point: regs hold final state
        bool last = false;
        if (f2prev == 0) {              // period-2 cycle: s(k-1)==s(k-3)
            if ((k & 1) == 0) break;    // s(499) == s(k-1) == current regs
            last = true;                // s(499) == s(k): finish this iter
        }

        int dV = 0, d2V = 0;
#pragma unroll
        for (int c = 0; c < 8; ++c) {
            float m0 = sm.sk.mVm[C0 + c], m1 = sm.sk.mVm[NMAXN + C0 + c];
            float s0 = sm.sk.mVs[C0 + c], s1 = sm.sk.mVs[NMAXN + C0 + c];
            float dm = m0 - m1;
            float m  = fmaxf(m0, m1);
            float e  = fexp2(-fabsf(dm));
            float s  = (dm >= 0.f) ? fmaf(s1, e, s0) : fmaf(s0, e, s1);
            float vn = lb[c] - (m + flog2(s));
            dV  |= (__float_as_uint(vn) != __float_as_uint(v_old[c]));
            d2V |= (__float_as_uint(vn) != __float_as_uint(v_p2[c]));
            v_p2[c]  = v_old[c];
            v_old[c] = vn;
        }

        // ========== phase U: u_i = la_i - lse_j(lk_ij + v_j) ==========
        float mr[8], sr[8];
#pragma unroll
        for (int r = 0; r < 8; ++r) { tt[r][0] = lk[r][0] + v_old[0]; mr[r] = tt[r][0]; }
#pragma unroll
        for (int c = 1; c < 8; ++c)
#pragma unroll
            for (int r = 0; r < 8; ++r) {
                tt[r][c] = lk[r][c] + v_old[c];
                mr[r] = fmaxf(mr[r], tt[r][c]);
            }
#pragma unroll
        for (int r = 0; r < 8; ++r) {   // in-wave reduce over tx8 (cols)
            mr[r] = fmaxf(mr[r], __shfl_xor(mr[r], 1));
            mr[r] = fmaxf(mr[r], __shfl_xor(mr[r], 2));
            mr[r] = fmaxf(mr[r], __shfl_xor(mr[r], 4));
        }
#pragma unroll
        for (int r = 0; r < 8; ++r) sr[r] = fexp2(tt[r][0] - mr[r]);
#pragma unroll
        for (int c = 1; c < 8; ++c)
#pragma unroll
            for (int r = 0; r < 8; ++r) sr[r] += fexp2(tt[r][c] - mr[r]);
#pragma unroll
        for (int r = 0; r < 8; ++r) {
            sr[r] += __shfl_xor(sr[r], 1);
            sr[r] += __shfl_xor(sr[r], 2);
            sr[r] += __shfl_xor(sr[r], 4);
        }
        if (tx8 == 0) {
#pragma unroll
            for (int r = 0; r < 8; ++r) {
                sm.sk.mUm[halfC * NMAXN + R0 + r] = mr[r];
                sm.sk.mUs[halfC * NMAXN + R0 + r] = sr[r];
            }
        }
        __syncthreads();                               // B2

        int dU = 0, d2U = 0;
#pragma unroll
        for (int r = 0; r < 8; ++r) {
            float m0 = sm.sk.mUm[R0 + r], m1 = sm.sk.mUm[NMAXN + R0 + r];
            float s0 = sm.sk.mUs[R0 + r], s1 = sm.sk.mUs[NMAXN + R0 + r];
            float dm = m0 - m1;
            float m  = fmaxf(m0, m1);
            float e  = fexp2(-fabsf(dm));
            float s  = (dm >= 0.f) ? fmaf(s1, e, s0) : fmaf(s0, e, s1);
            float un = la[r] - (m + flog2(s));
            dU  |= (__float_as_uint(un) != __float_as_uint(u_old[r]));
            d2U |= (__float_as_uint(un) != __float_as_uint(u_p2[r]));
            u_p2[r]  = u_old[r];
            u_old[r] = un;
        }

        // flag publication for iter k (read at iter k+1 after its B1)
        if (__any(dV | dU))   { if (lane == 0) flagsA[k & 1] = 1; }
        if (__any(d2V | d2U)) { if (lane == 0) flagsB[k & 1] = 1; }
        if (tid == 0) { flagsA[(k + 1) & 1] = 0; flagsB[(k + 1) & 1] = 0; }

        if (last) break;
    }

    // ---- epilogue: out_b = OUTSC * sum_ij lk_ij * 2^(lk+u+v) ----
    float acc = 0.f;
#pragma unroll
    for (int r = 0; r < 8; ++r)
#pragma unroll
        for (int c = 0; c < 8; ++c)
            acc += lk[r][c] * fexp2(lk[r][c] + u_old[r] + v_old[c]);
#pragma unroll
    for (int d = 1; d < 64; d <<= 1) acc += __shfl_xor(acc, d);
    if (lane == 0) swred[w] = acc;
    __syncthreads();
    if (tid == 0) out[b] = (swred[0] + swred[1] + swred[2] + swred[3]) * OUTSC;
}

extern "C" void kernel_launch(void* const* d_in, const int* in_sizes, int n_in,
                              void* d_out, int out_size, void* d_ws, size_t ws_size,
                              hipStream_t stream) {
    const float* x1  = (const float*)d_in[0];
    const float* x2  = (const float*)d_in[1];
    const int*   sz1 = (const int*)d_in[2];
    const int*   sz2 = (const int*)d_in[3];
    float* out = (float*)d_out;
    hipLaunchKernelGGL(wasserstein_kernel, dim3(512), dim3(256), 0, stream,
                       x1, x2, sz1, sz2, out);
}

// Round 3
// 2333.030 us; speedup vs baseline: 1.5361x; 1.5361x over previous
//
#include <hip/hip_runtime.h>

#ifndef __has_builtin
#define __has_builtin(x) 0
#endif

__device__ __forceinline__ float fexp2(float x) {
#if __has_builtin(__builtin_amdgcn_exp2f)
    return __builtin_amdgcn_exp2f(x);   // v_exp_f32 (2^x)
#else
    return exp2f(x);
#endif
}
__device__ __forceinline__ float flog2(float x) {
#if __has_builtin(__builtin_amdgcn_logf)
    return __builtin_amdgcn_logf(x);    // v_log_f32 (log2 x)
#else
    return log2f(x);
#endif
}

#define NMAXN 128
#define DD    64
#define MAX_ITERS 500

// -1e5 * log2(e)  (NEG surrogate in log2 domain)
#define NEG2  (-144269.50408889634f)
// -(log2(e) / eps), eps = 1e-3 : logK2 = M * LKSC
#define LKSC  (-1442.6950408889634f)
// -(eps * ln2) : out = acc * OUTSC
#define OUTSC (-6.931471805599453e-4f)

struct SmemStage {
    float A[NMAXN * 33];   // set1 chunk [128][32] padded
    float B[NMAXN * 33];   // set2 chunk
    float nA[NMAXN];       // row norms set1
    float nB[NMAXN];       // row norms set2
};
struct SmemSink {
    // u-phase cross-wave partials, [buf][wave*128 + r*16 + rg] -> (max, sum)
    // stride-1 in rg across lanes => conflict-free reads AND writes
    float2 part[2][512];
};
union SmemU {
    SmemStage st;
    SmemSink  sk;
};

__global__ __launch_bounds__(256, 2)
void wasserstein_kernel(const float* __restrict__ x1, const float* __restrict__ x2,
                        const int* __restrict__ sz1, const int* __restrict__ sz2,
                        float* __restrict__ out)
{
    __shared__ SmemU sm;
    __shared__ int   soff[8];
    __shared__ float swred[4];

    const int b    = blockIdx.x;
    const int tid  = threadIdx.x;
    const int w    = tid >> 6;        // wave 0..3
    const int lane = tid & 63;
    const int rg   = lane >> 2;       // row-group 0..15  -> rows 8rg..8rg+7
    const int cg   = lane & 3;        // col-group 0..3
    const int R0   = rg << 3;                 // first owned row (all waves span all rows)
    const int C0   = (w << 5) | (cg << 3);    // first owned col (wave owns 32-col slab)

    // ---- exclusive prefix sums of sizes (ragged offsets) ----
    int a1 = 0, a2 = 0;
    for (int kk = tid; kk < b; kk += 256) { a1 += sz1[kk]; a2 += sz2[kk]; }
#pragma unroll
    for (int d = 1; d < 64; d <<= 1) {
        a1 += __shfl_xor(a1, d);
        a2 += __shfl_xor(a2, d);
    }
    if (lane == 0) { soff[w] = a1; soff[4 + w] = a2; }
    if (tid < NMAXN) { sm.st.nA[tid] = 0.f; sm.st.nB[tid] = 0.f; }
    __syncthreads();
    const int off1 = soff[0] + soff[1] + soff[2] + soff[3];
    const int off2 = soff[4] + soff[5] + soff[6] + soff[7];
    const int n1 = sz1[b];
    const int n2 = sz2[b];

    // ---- stage sets in D-chunks of 32, accumulate dots + norms ----
    float lk[8][8];   // starts as dot accumulator, becomes logK2
#pragma unroll
    for (int r = 0; r < 8; ++r)
#pragma unroll
        for (int c = 0; c < 8; ++c) lk[r][c] = 0.f;

    const int srow  = tid >> 1;  // 0..127
    const int shalf = tid & 1;   // 16-float half of chunk

    for (int ch = 0; ch < 2; ++ch) {
        const float* p1 = x1 + (size_t)(off1 + srow) * DD + ch * 32 + shalf * 16;
        const float* p2 = x2 + (size_t)(off2 + srow) * DD + ch * 32 + shalf * 16;
        const bool ok1 = srow < n1;
        const bool ok2 = srow < n2;
        float va[16], vb[16];
#pragma unroll
        for (int q = 0; q < 4; ++q) {
            float4 t1 = ok1 ? ((const float4*)p1)[q] : make_float4(0.f, 0.f, 0.f, 0.f);
            float4 t2 = ok2 ? ((const float4*)p2)[q] : make_float4(0.f, 0.f, 0.f, 0.f);
            va[4*q+0] = t1.x; va[4*q+1] = t1.y; va[4*q+2] = t1.z; va[4*q+3] = t1.w;
            vb[4*q+0] = t2.x; vb[4*q+1] = t2.y; vb[4*q+2] = t2.z; vb[4*q+3] = t2.w;
        }
        float s1 = 0.f, s2 = 0.f;
        const int cb = shalf * 16;
#pragma unroll
        for (int q = 0; q < 16; ++q) {
            sm.st.A[srow * 33 + cb + q] = va[q];
            sm.st.B[srow * 33 + cb + q] = vb[q];
            s1 += va[q] * va[q];
            s2 += vb[q] * vb[q];
        }
        s1 += __shfl_xor(s1, 1);
        s2 += __shfl_xor(s2, 1);
        if (shalf == 0) { sm.st.nA[srow] += s1; sm.st.nB[srow] += s2; }
        __syncthreads();
#pragma unroll 2
        for (int d = 0; d < 32; ++d) {
            float av[8], bv[8];
#pragma unroll
            for (int r = 0; r < 8; ++r) av[r] = sm.st.A[(R0 + r) * 33 + d];
#pragma unroll
            for (int c = 0; c < 8; ++c) bv[c] = sm.st.B[(C0 + c) * 33 + d];
#pragma unroll
            for (int r = 0; r < 8; ++r)
#pragma unroll
                for (int c = 0; c < 8; ++c)
                    lk[r][c] = fmaf(av[r], bv[c], lk[r][c]);
        }
        __syncthreads();
    }

    // logK2 = -M * log2e/eps, M = ||a||^2 + ||b||^2 - 2ab (clamped >= 0)
    {
        float rn1[8], rn2[8];
#pragma unroll
        for (int r = 0; r < 8; ++r) rn1[r] = sm.st.nA[R0 + r];
#pragma unroll
        for (int c = 0; c < 8; ++c) rn2[c] = sm.st.nB[C0 + c];
#pragma unroll
        for (int r = 0; r < 8; ++r)
#pragma unroll
            for (int c = 0; c < 8; ++c) {
                float M = rn1[r] + rn2[c] - 2.f * lk[r][c];
                lk[r][c] = fmaxf(M, 0.f) * LKSC;
            }
    }
    __syncthreads();   // retire staging view of the union before part[] writes

    // ---- Sinkhorn (log2 domain); u,v in registers; 1 barrier/iter ----
    const float lbv = flog2((float)n1) - flog2((float)n2);
    float u[8], v[8];
#pragma unroll
    for (int r = 0; r < 8; ++r) u[r] = 0.f;

    for (int k = 0; k < MAX_ITERS; ++k) {
        // ===== phase V (pure in-wave): v_j = lb_j - lse_i(lk_ij + u_i) =====
        float mx[8], sc[8];
#pragma unroll
        for (int c = 0; c < 8; ++c) mx[c] = lk[0][c] + u[0];
#pragma unroll
        for (int r = 1; r < 8; ++r)
#pragma unroll
            for (int c = 0; c < 8; ++c)
                mx[c] = fmaxf(mx[c], lk[r][c] + u[r]);
#pragma unroll
        for (int c = 0; c < 8; ++c) {   // reduce across 16 row-groups
            mx[c] = fmaxf(mx[c], __shfl_xor(mx[c], 4));
            mx[c] = fmaxf(mx[c], __shfl_xor(mx[c], 8));
            mx[c] = fmaxf(mx[c], __shfl_xor(mx[c], 16));
            mx[c] = fmaxf(mx[c], __shfl_xor(mx[c], 32));
        }
#pragma unroll
        for (int c = 0; c < 8; ++c) sc[c] = fexp2(lk[0][c] + u[0] - mx[c]);
#pragma unroll
        for (int r = 1; r < 8; ++r)
#pragma unroll
            for (int c = 0; c < 8; ++c)
                sc[c] += fexp2(lk[r][c] + u[r] - mx[c]);
#pragma unroll
        for (int c = 0; c < 8; ++c) {
            sc[c] += __shfl_xor(sc[c], 4);
            sc[c] += __shfl_xor(sc[c], 8);
            sc[c] += __shfl_xor(sc[c], 16);
            sc[c] += __shfl_xor(sc[c], 32);
        }
#pragma unroll
        for (int c = 0; c < 8; ++c) {
            float lbc = (C0 + c < n2) ? lbv : NEG2;
            v[c] = lbc - (mx[c] + flog2(sc[c]));
        }

        // ===== phase U: u_i = la_i - lse_j(lk_ij + v_j), cross-wave =====
        float mr[8], sr[8];
#pragma unroll
        for (int r = 0; r < 8; ++r) mr[r] = lk[r][0] + v[0];
#pragma unroll
        for (int c = 1; c < 8; ++c)
#pragma unroll
            for (int r = 0; r < 8; ++r)
                mr[r] = fmaxf(mr[r], lk[r][c] + v[c]);
#pragma unroll
        for (int r = 0; r < 8; ++r) {   // reduce across 4 col-groups
            mr[r] = fmaxf(mr[r], __shfl_xor(mr[r], 1));
            mr[r] = fmaxf(mr[r], __shfl_xor(mr[r], 2));
        }
#pragma unroll
        for (int r = 0; r < 8; ++r) sr[r] = fexp2(lk[r][0] + v[0] - mr[r]);
#pragma unroll
        for (int c = 1; c < 8; ++c)
#pragma unroll
            for (int r = 0; r < 8; ++r)
                sr[r] += fexp2(lk[r][c] + v[c] - mr[r]);
#pragma unroll
        for (int r = 0; r < 8; ++r) {
            sr[r] += __shfl_xor(sr[r], 1);
            sr[r] += __shfl_xor(sr[r], 2);
        }
        if (cg == 0) {
#pragma unroll
            for (int r = 0; r < 8; ++r)
                sm.sk.part[k & 1][(w << 7) | (r << 4) | rg] = make_float2(mr[r], sr[r]);
        }
        __syncthreads();   // the ONLY barrier per iteration

        // combine 4 wave-partials per owned row -> u
#pragma unroll
        for (int r = 0; r < 8; ++r) {
            float2 p0 = sm.sk.part[k & 1][(0 << 7) | (r << 4) | rg];
            float2 p1 = sm.sk.part[k & 1][(1 << 7) | (r << 4) | rg];
            float2 p2 = sm.sk.part[k & 1][(2 << 7) | (r << 4) | rg];
            float2 p3 = sm.sk.part[k & 1][(3 << 7) | (r << 4) | rg];
            float m = fmaxf(fmaxf(p0.x, p1.x), fmaxf(p2.x, p3.x));
            float s = p0.y * fexp2(p0.x - m);
            s = fmaf(p1.y, fexp2(p1.x - m), s);
            s = fmaf(p2.y, fexp2(p2.x - m), s);
            s = fmaf(p3.y, fexp2(p3.x - m), s);
            float lar = (R0 + r < n1) ? 0.f : NEG2;
            u[r] = lar - (m + flog2(s));
        }
    }

    // ---- epilogue: out_b = OUTSC * sum_ij lk_ij * 2^(lk+u+v) ----
    float acc = 0.f;
#pragma unroll
    for (int r = 0; r < 8; ++r)
#pragma unroll
        for (int c = 0; c < 8; ++c)
            acc += lk[r][c] * fexp2(lk[r][c] + u[r] + v[c]);
#pragma unroll
    for (int d = 1; d < 64; d <<= 1) acc += __shfl_xor(acc, d);
    if (lane == 0) swred[w] = acc;
    __syncthreads();
    if (tid == 0) out[b] = (swred[0] + swred[1] + swred[2] + swred[3]) * OUTSC;
}

extern "C" void kernel_launch(void* const* d_in, const int* in_sizes, int n_in,
                              void* d_out, int out_size, void* d_ws, size_t ws_size,
                              hipStream_t stream) {
    const float* x1  = (const float*)d_in[0];
    const float* x2  = (const float*)d_in[1];
    const int*   sz1 = (const int*)d_in[2];
    const int*   sz2 = (const int*)d_in[3];
    float* out = (float*)d_out;
    hipLaunchKernelGGL(wasserstein_kernel, dim3(512), dim3(256), 0, stream,
                       x1, x2, sz1, sz2, out);
}

// Round 4
// 2327.688 us; speedup vs baseline: 1.5396x; 1.0023x over previous
//
#include <hip/hip_runtime.h>

#ifndef __has_builtin
#define __has_builtin(x) 0
#endif

__device__ __forceinline__ float fexp2(float x) {
#if __has_builtin(__builtin_amdgcn_exp2f)
    return __builtin_amdgcn_exp2f(x);   // v_exp_f32 (2^x)
#else
    return exp2f(x);
#endif
}
__device__ __forceinline__ float flog2(float x) {
#if __has_builtin(__builtin_amdgcn_logf)
    return __builtin_amdgcn_logf(x);    // v_log_f32 (log2 x)
#else
    return log2f(x);
#endif
}

#define NMAXN 128
#define DD    64
#define MAX_ITERS 500

// -1e5 * log2(e)  (NEG surrogate in log2 domain)
#define NEG2  (-144269.50408889634f)
// -(log2(e) / eps), eps = 1e-3 : logK2 = M * LKSC
#define LKSC  (-1442.6950408889634f)
// -(eps * ln2) : out = acc * OUTSC
#define OUTSC (-6.931471805599453e-4f)

struct SmemStage {
    float A[NMAXN * 33];   // set1 chunk [128][32] padded
    float B[NMAXN * 33];   // set2 chunk
    float nA[NMAXN];       // row norms set1
    float nB[NMAXN];       // row norms set2
};
struct SmemSink {
    // [buf][row*5 + w] -> (max,sum). stride 5 (x10 words) => 16 distinct banks
    // across rg, 4-way same-bank alias from cg (free-ish), broadcast reads.
    float2 part[2][NMAXN * 5];
};
union SmemU {
    SmemStage st;
    SmemSink  sk;
};

// ---------------- schedule pre-kernel: sort batches by work ----------------
__global__ void schedule_kernel(const int* __restrict__ sz1,
                                const int* __restrict__ sz2,
                                int* __restrict__ sched)
{
    __shared__ int keys[512];
    const int t = threadIdx.x;
    const int n1 = sz1[t], n2 = sz2[t];
    const int work = ((n1 + 15) >> 4) * ((n2 + 15) >> 4);   // 16..64
    keys[t] = (work << 16) | t;
    __syncthreads();
    for (int kk = 2; kk <= 512; kk <<= 1) {
        for (int j = kk >> 1; j > 0; j >>= 1) {
            int ixj = t ^ j;
            if (ixj > t) {
                int a = keys[t], b = keys[ixj];
                bool asc = ((t & kk) == 0);
                if ((a > b) == asc) { keys[t] = b; keys[ixj] = a; }
            }
            __syncthreads();
        }
    }
    // stripe: first 256 block slots = heaviest (desc), last 256 = lightest (asc)
    sched[t] = (t < 256) ? (keys[511 - t] & 0xFFFF) : (keys[t - 256] & 0xFFFF);
}

// ---------------- Sinkhorn core, templated on col strip count -------------
template<int CMAX>
__device__ __forceinline__ void run_core(
    float (&lk)[8][8], const float (&la)[8], const float (&lb)[8],
    const float (&mpad)[8], float p1f, int rmax,
    int rg, int cg, int w, int tid,
    SmemU* smu, float* swred, float* out, int outb)
{
    float u[8], v[8];
#pragma unroll
    for (int r = 0; r < 8; ++r) u[r] = 0.f;

    for (int k = 0; k < MAX_ITERS; ++k) {
        // ===== phase V: v_j = lb_j - lse_r(lk[r][j] + u[r]) (in-wave) =====
        float mx[CMAX], sc[CMAX];
#pragma unroll
        for (int c = 0; c < CMAX; ++c) mx[c] = lk[0][c] + u[0];
#pragma unroll
        for (int r = 1; r < 4; ++r)
#pragma unroll
            for (int c = 0; c < CMAX; ++c)
                mx[c] = fmaxf(mx[c], lk[r][c] + u[r]);
        if (rmax > 4) {
#pragma unroll
            for (int c = 0; c < CMAX; ++c) mx[c] = fmaxf(mx[c], lk[4][c] + u[4]);
            if (rmax > 5) {
#pragma unroll
                for (int c = 0; c < CMAX; ++c) mx[c] = fmaxf(mx[c], lk[5][c] + u[5]);
                if (rmax > 6) {
#pragma unroll
                    for (int c = 0; c < CMAX; ++c) mx[c] = fmaxf(mx[c], lk[6][c] + u[6]);
                    if (rmax > 7) {
#pragma unroll
                        for (int c = 0; c < CMAX; ++c) mx[c] = fmaxf(mx[c], lk[7][c] + u[7]);
                    }
                }
            }
        }
#pragma unroll
        for (int c = 0; c < CMAX; ++c) {   // reduce over 16 row-groups (lane bits 2..5)
            mx[c] = fmaxf(mx[c], __shfl_xor(mx[c], 4));
            mx[c] = fmaxf(mx[c], __shfl_xor(mx[c], 8));
            mx[c] = fmaxf(mx[c], __shfl_xor(mx[c], 16));
            mx[c] = fmaxf(mx[c], __shfl_xor(mx[c], 32));
        }
#pragma unroll
        for (int c = 0; c < CMAX; ++c) sc[c] = fexp2(lk[0][c] + u[0] - mx[c]);
#pragma unroll
        for (int r = 1; r < 4; ++r)
#pragma unroll
            for (int c = 0; c < CMAX; ++c)
                sc[c] += fexp2(lk[r][c] + u[r] - mx[c]);
        if (rmax > 4) {
#pragma unroll
            for (int c = 0; c < CMAX; ++c) sc[c] += fexp2(lk[4][c] + u[4] - mx[c]);
            if (rmax > 5) {
#pragma unroll
                for (int c = 0; c < CMAX; ++c) sc[c] += fexp2(lk[5][c] + u[5] - mx[c]);
                if (rmax > 6) {
#pragma unroll
                    for (int c = 0; c < CMAX; ++c) sc[c] += fexp2(lk[6][c] + u[6] - mx[c]);
                    if (rmax > 7) {
#pragma unroll
                        for (int c = 0; c < CMAX; ++c) sc[c] += fexp2(lk[7][c] + u[7] - mx[c]);
                    }
                }
            }
        }
#pragma unroll
        for (int c = 0; c < CMAX; ++c) {
            sc[c] += __shfl_xor(sc[c], 4);
            sc[c] += __shfl_xor(sc[c], 8);
            sc[c] += __shfl_xor(sc[c], 16);
            sc[c] += __shfl_xor(sc[c], 32);
        }
        if (k == 0 && p1f > 0.5f) {
            // analytic fold of the (128-16*rmax) non-materialized pad rows
            // (zero vectors, u=0): candidate m_pad = ||b_c||^2 * LKSC
#pragma unroll
            for (int c = 0; c < CMAX; ++c) {
                float mm = fmaxf(mx[c], mpad[c]);
                sc[c] = sc[c] * fexp2(mx[c] - mm) + p1f * fexp2(mpad[c] - mm);
                mx[c] = mm;
            }
        }
#pragma unroll
        for (int c = 0; c < CMAX; ++c)
            v[c] = lb[c] - (mx[c] + flog2(sc[c]));

        // ===== phase U: u_r = la_r - lse_c(lk[r][c] + v[c]) =====
        float mr[8], sr[8];
#define U_STRIP(r)                                                          \
        {                                                                   \
            float m_ = lk[r][0] + v[0];                                     \
            _Pragma("unroll")                                               \
            for (int c = 1; c < CMAX; ++c) m_ = fmaxf(m_, lk[r][c] + v[c]); \
            m_ = fmaxf(m_, __shfl_xor(m_, 1));                              \
            m_ = fmaxf(m_, __shfl_xor(m_, 2));                              \
            float s_ = fexp2(lk[r][0] + v[0] - m_);                         \
            _Pragma("unroll")                                               \
            for (int c = 1; c < CMAX; ++c) s_ += fexp2(lk[r][c] + v[c] - m_);\
            s_ += __shfl_xor(s_, 1);                                        \
            s_ += __shfl_xor(s_, 2);                                        \
            mr[r] = m_; sr[r] = s_;                                         \
        }
        U_STRIP(0) U_STRIP(1) U_STRIP(2) U_STRIP(3)
        if (rmax > 4) { U_STRIP(4)
            if (rmax > 5) { U_STRIP(5)
                if (rmax > 6) { U_STRIP(6)
                    if (rmax > 7) { U_STRIP(7) } } } }
#undef U_STRIP

        float2* pb = smu->sk.part[k & 1];
        pb[(rg + 16 * cg) * 5 + w] = make_float2(mr[cg], sr[cg]);
        if (cg + 4 < rmax)
            pb[(rg + 16 * (cg + 4)) * 5 + w] = make_float2(mr[cg + 4], sr[cg + 4]);
        __syncthreads();   // the ONLY barrier per iteration

#define C_STRIP(r)                                                          \
        {                                                                   \
            const float2* pr = &pb[(rg + 16 * (r)) * 5];                    \
            float2 p0 = pr[0], p1 = pr[1], p2 = pr[2], p3 = pr[3];          \
            float m_ = fmaxf(fmaxf(p0.x, p1.x), fmaxf(p2.x, p3.x));         \
            float s_ = p0.y * fexp2(p0.x - m_);                             \
            s_ = fmaf(p1.y, fexp2(p1.x - m_), s_);                          \
            s_ = fmaf(p2.y, fexp2(p2.x - m_), s_);                          \
            s_ = fmaf(p3.y, fexp2(p3.x - m_), s_);                          \
            u[r] = la[r] - (m_ + flog2(s_));                                \
        }
        C_STRIP(0) C_STRIP(1) C_STRIP(2) C_STRIP(3)
        if (rmax > 4) { C_STRIP(4)
            if (rmax > 5) { C_STRIP(5)
                if (rmax > 6) { C_STRIP(6)
                    if (rmax > 7) { C_STRIP(7) } } } }
#undef C_STRIP
    }

    // ---- epilogue: out = OUTSC * sum lk * 2^(lk+u+v) over valid slots ----
    float acc = 0.f;
#define E_STRIP(r)                                                          \
        _Pragma("unroll")                                                   \
        for (int c = 0; c < CMAX; ++c)                                      \
            acc += lk[r][c] * fexp2(lk[r][c] + u[r] + v[c]);
    E_STRIP(0) E_STRIP(1) E_STRIP(2) E_STRIP(3)
    if (rmax > 4) { E_STRIP(4)
        if (rmax > 5) { E_STRIP(5)
            if (rmax > 6) { E_STRIP(6)
                if (rmax > 7) { E_STRIP(7) } } } }
#undef E_STRIP
#pragma unroll
    for (int d = 1; d < 64; d <<= 1) acc += __shfl_xor(acc, d);
    if ((tid & 63) == 0) swred[w] = acc;
    __syncthreads();
    if (tid == 0) out[outb] = (swred[0] + swred[1] + swred[2] + swred[3]) * OUTSC;
}

__global__ __launch_bounds__(256, 2)
void wasserstein_kernel(const float* __restrict__ x1, const float* __restrict__ x2,
                        const int* __restrict__ sz1, const int* __restrict__ sz2,
                        const int* __restrict__ sched,
                        float* __restrict__ out)
{
    __shared__ SmemU sm;
    __shared__ int   soff[8];
    __shared__ float swred[4];

    const int b    = sched[blockIdx.x];   // balanced batch assignment
    const int tid  = threadIdx.x;
    const int w    = tid >> 6;        // wave 0..3
    const int lane = tid & 63;
    const int rg   = lane >> 2;       // 0..15: rows rg + 16*r
    const int cg   = lane & 3;        // 0..3 : cols w*4+cg + 16*c
    const int W4   = (w << 2) | cg;   // 0..15

    // ---- exclusive prefix sums of sizes (ragged offsets) ----
    int a1 = 0, a2 = 0;
    for (int kk = tid; kk < b; kk += 256) { a1 += sz1[kk]; a2 += sz2[kk]; }
#pragma unroll
    for (int d = 1; d < 64; d <<= 1) {
        a1 += __shfl_xor(a1, d);
        a2 += __shfl_xor(a2, d);
    }
    if (lane == 0) { soff[w] = a1; soff[4 + w] = a2; }
    if (tid < NMAXN) { sm.st.nA[tid] = 0.f; sm.st.nB[tid] = 0.f; }
    __syncthreads();
    const int off1 = soff[0] + soff[1] + soff[2] + soff[3];
    const int off2 = soff[4] + soff[5] + soff[6] + soff[7];
    const int n1 = sz1[b];
    const int n2 = sz2[b];
    const int rmax = (n1 + 15) >> 4;   // 4..8
    const int cmax = (n2 + 15) >> 4;   // 4..8

    // ---- stage sets in D-chunks of 32, accumulate dots + norms ----
    float lk[8][8];
#pragma unroll
    for (int r = 0; r < 8; ++r)
#pragma unroll
        for (int c = 0; c < 8; ++c) lk[r][c] = 0.f;

    const int srow  = tid >> 1;  // 0..127
    const int shalf = tid & 1;   // 16-float half of chunk

    for (int ch = 0; ch < 2; ++ch) {
        const float* p1 = x1 + (size_t)(off1 + srow) * DD + ch * 32 + shalf * 16;
        const float* p2 = x2 + (size_t)(off2 + srow) * DD + ch * 32 + shalf * 16;
        const bool ok1 = srow < n1;
        const bool ok2 = srow < n2;
        float va[16], vb[16];
#pragma unroll
        for (int q = 0; q < 4; ++q) {
            float4 t1 = ok1 ? ((const float4*)p1)[q] : make_float4(0.f, 0.f, 0.f, 0.f);
            float4 t2 = ok2 ? ((const float4*)p2)[q] : make_float4(0.f, 0.f, 0.f, 0.f);
            va[4*q+0] = t1.x; va[4*q+1] = t1.y; va[4*q+2] = t1.z; va[4*q+3] = t1.w;
            vb[4*q+0] = t2.x; vb[4*q+1] = t2.y; vb[4*q+2] = t2.z; vb[4*q+3] = t2.w;
        }
        float s1 = 0.f, s2 = 0.f;
        const int cb = shalf * 16;
#pragma unroll
        for (int q = 0; q < 16; ++q) {
            sm.st.A[srow * 33 + cb + q] = va[q];
            sm.st.B[srow * 33 + cb + q] = vb[q];
            s1 += va[q] * va[q];
            s2 += vb[q] * vb[q];
        }
        s1 += __shfl_xor(s1, 1);
        s2 += __shfl_xor(s2, 1);
        if (shalf == 0) { sm.st.nA[srow] += s1; sm.st.nB[srow] += s2; }
        __syncthreads();
#pragma unroll 2
        for (int d = 0; d < 32; ++d) {
            float av[8], bv[8];
#pragma unroll
            for (int r = 0; r < 8; ++r) av[r] = sm.st.A[(rg + 16*r) * 33 + d];
#pragma unroll
            for (int c = 0; c < 8; ++c) bv[c] = sm.st.B[(W4 + 16*c) * 33 + d];
#pragma unroll
            for (int r = 0; r < 8; ++r)
#pragma unroll
                for (int c = 0; c < 8; ++c)
                    lk[r][c] = fmaf(av[r], bv[c], lk[r][c]);
        }
        __syncthreads();
    }

    // logK2 = -M*log2e/eps, M = ||a||^2+||b||^2-2ab (clamped), + pad/mask data
    float la[8], lb[8], mpad[8];
    const float lbv = flog2((float)n1) - flog2((float)n2);
    {
        float rn1[8], rn2[8];
#pragma unroll
        for (int r = 0; r < 8; ++r) rn1[r] = sm.st.nA[rg + 16*r];
#pragma unroll
        for (int c = 0; c < 8; ++c) rn2[c] = sm.st.nB[W4 + 16*c];
#pragma unroll
        for (int r = 0; r < 8; ++r)
#pragma unroll
            for (int c = 0; c < 8; ++c) {
                float M = rn1[r] + rn2[c] - 2.f * lk[r][c];
                lk[r][c] = fmaxf(M, 0.f) * LKSC;
            }
#pragma unroll
        for (int r = 0; r < 8; ++r) la[r] = (rg + 16*r < n1) ? 0.f : NEG2;
#pragma unroll
        for (int c = 0; c < 8; ++c) {
            lb[c]   = (W4 + 16*c < n2) ? lbv : NEG2;
            mpad[c] = rn2[c] * LKSC;
        }
    }
    const float p1f = (float)(NMAXN - 16 * rmax);
    __syncthreads();   // retire staging view of the union

    switch (cmax) {
        case 4: run_core<4>(lk, la, lb, mpad, p1f, rmax, rg, cg, w, tid, &sm, swred, out, b); break;
        case 5: run_core<5>(lk, la, lb, mpad, p1f, rmax, rg, cg, w, tid, &sm, swred, out, b); break;
        case 6: run_core<6>(lk, la, lb, mpad, p1f, rmax, rg, cg, w, tid, &sm, swred, out, b); break;
        case 7: run_core<7>(lk, la, lb, mpad, p1f, rmax, rg, cg, w, tid, &sm, swred, out, b); break;
        default: run_core<8>(lk, la, lb, mpad, p1f, rmax, rg, cg, w, tid, &sm, swred, out, b); break;
    }
}

extern "C" void kernel_launch(void* const* d_in, const int* in_sizes, int n_in,
                              void* d_out, int out_size, void* d_ws, size_t ws_size,
                              hipStream_t stream) {
    const float* x1  = (const float*)d_in[0];
    const float* x2  = (const float*)d_in[1];
    const int*   sz1 = (const int*)d_in[2];
    const int*   sz2 = (const int*)d_in[3];
    float* out  = (float*)d_out;
    int* sched  = (int*)d_ws;
    hipLaunchKernelGGL(schedule_kernel, dim3(1), dim3(512), 0, stream, sz1, sz2, sched);
    hipLaunchKernelGGL(wasserstein_kernel, dim3(512), dim3(256), 0, stream,
                       x1, x2, sz1, sz2, sched, out);
}